// Round 1
// baseline (974.594 us; speedup 1.0000x reference)
//
#include <hip/hip_runtime.h>
#include <hip/hip_bf16.h>

// CircuitGNN: 3-layer GCN (N=500k, E=1M, H=64) + mean pool + tanh FC head.
// Strategy:
//   - GCN layer = S @ h @ W + b with S = normalized adjacency (incl self loops).
//   - Use linearity: compute a = S@h first (gather via CSR), then h' = relu(a@W + b).
//   - CSR built once per call: degree histogram (atomics) -> exclusive scan -> fill.
//   - Layer 3 matmul fused with mean-pool (h3 never materialized).
// All fp32 (no fp32 MFMA on CDNA4; matmuls are register-tiled vector FMA).

#define ALIGN256(x) (((x) + 255) & ~(size_t)255)

__global__ __launch_bounds__(256) void deg_kernel(const int* __restrict__ dst, int* __restrict__ cnt, int E) {
    int e = blockIdx.x * 256 + threadIdx.x;
    if (e < E) atomicAdd(&cnt[dst[e]], 1);
}

__global__ __launch_bounds__(256) void dinv_kernel(const int* __restrict__ cnt, float* __restrict__ dinv, int N) {
    int i = blockIdx.x * 256 + threadIdx.x;
    if (i < N) dinv[i] = rsqrtf((float)(cnt[i] + 1));   // +1 = self loop
}

// ---- 2-level exclusive scan over cnt[N] (N <= 512*1024) ----
__global__ __launch_bounds__(256) void scan1_kernel(const int* __restrict__ cnt, int* __restrict__ bsum, int N) {
    __shared__ int s[256];
    int t = threadIdx.x, b = blockIdx.x;
    int i0 = b * 1024 + t * 4;
    int v = 0;
    if (i0 + 3 < N) { int4 q = *(const int4*)&cnt[i0]; v = q.x + q.y + q.z + q.w; }
    else { for (int k = 0; k < 4; ++k) if (i0 + k < N) v += cnt[i0 + k]; }
    s[t] = v; __syncthreads();
    for (int o = 128; o > 0; o >>= 1) { if (t < o) s[t] += s[t + o]; __syncthreads(); }
    if (t == 0) bsum[b] = s[0];
}

__global__ __launch_bounds__(512) void scan2_kernel(const int* __restrict__ bsum, int* __restrict__ bbase, int nb) {
    __shared__ int s[512];
    int t = threadIdx.x;
    int v = (t < nb) ? bsum[t] : 0;
    s[t] = v; __syncthreads();
    for (int off = 1; off < 512; off <<= 1) {
        int u = 0; if (t >= off) u = s[t - off];
        __syncthreads(); s[t] += u; __syncthreads();
    }
    if (t < nb) bbase[t] = s[t] - v;   // exclusive
}

__global__ __launch_bounds__(256) void scan3_kernel(const int* __restrict__ cnt, const int* __restrict__ bbase,
                                                    int* __restrict__ offs, int* __restrict__ cur, int N) {
    __shared__ int s[256];
    int t = threadIdx.x, b = blockIdx.x;
    int i0 = b * 1024 + t * 4;
    int v0 = 0, v1 = 0, v2 = 0, v3 = 0;
    if (i0 + 3 < N) { int4 q = *(const int4*)&cnt[i0]; v0 = q.x; v1 = q.y; v2 = q.z; v3 = q.w; }
    else {
        if (i0 < N) v0 = cnt[i0];
        if (i0 + 1 < N) v1 = cnt[i0 + 1];
        if (i0 + 2 < N) v2 = cnt[i0 + 2];
        if (i0 + 3 < N) v3 = cnt[i0 + 3];
    }
    int ts = v0 + v1 + v2 + v3;
    s[t] = ts; __syncthreads();
    for (int off = 1; off < 256; off <<= 1) {
        int u = 0; if (t >= off) u = s[t - off];
        __syncthreads(); s[t] += u; __syncthreads();
    }
    int ex = s[t] - ts + bbase[b];
    int o0 = ex, o1 = ex + v0, o2 = o1 + v1, o3 = o2 + v2;
    if (i0     < N) { offs[i0]     = o0; cur[i0]     = o0; }
    if (i0 + 1 < N) { offs[i0 + 1] = o1; cur[i0 + 1] = o1; }
    if (i0 + 2 < N) { offs[i0 + 2] = o2; cur[i0 + 2] = o2; }
    if (i0 + 3 < N) { offs[i0 + 3] = o3; cur[i0 + 3] = o3; }
}

__global__ __launch_bounds__(256) void fill_kernel(const int* __restrict__ ei, int* __restrict__ cur,
                                                   int* __restrict__ csr, int E) {
    int e = blockIdx.x * 256 + threadIdx.x;
    if (e < E) {
        int s = ei[e], d = ei[E + e];
        int p = atomicAdd(&cur[d], 1);
        csr[p] = s;
    }
}

// ---- layer 1: aggregate raw 3-wide x (thread per node) ----
__global__ __launch_bounds__(256) void agg1_kernel(const float* __restrict__ x, const float* __restrict__ dinv,
                                                   const int* __restrict__ offs, const int* __restrict__ cnt,
                                                   const int* __restrict__ csr, float* __restrict__ a1, int N) {
    int j = blockIdx.x * 256 + threadIdx.x;
    if (j >= N) return;
    float dj = dinv[j];
    float s0 = dj * x[(size_t)j * 3 + 0];
    float s1 = dj * x[(size_t)j * 3 + 1];
    float s2 = dj * x[(size_t)j * 3 + 2];
    int off = offs[j], deg = cnt[j];
    for (int i = 0; i < deg; ++i) {
        int s = csr[off + i];
        float ds = dinv[s];
        s0 += ds * x[(size_t)s * 3 + 0];
        s1 += ds * x[(size_t)s * 3 + 1];
        s2 += ds * x[(size_t)s * 3 + 2];
    }
    a1[(size_t)j * 4 + 0] = dj * s0;
    a1[(size_t)j * 4 + 1] = dj * s1;
    a1[(size_t)j * 4 + 2] = dj * s2;
}

// ---- layer 1 matmul 3->64, wave per node, fused bias+relu ----
__global__ __launch_bounds__(256) void mm1_kernel(const float* __restrict__ a1, const float* __restrict__ W1,
                                                  const float* __restrict__ b1, float* __restrict__ h, int N) {
    int j = blockIdx.x * 4 + (threadIdx.x >> 6);
    int l = threadIdx.x & 63;
    if (j >= N) return;
    float v = b1[l]
            + a1[(size_t)j * 4 + 0] * W1[l]
            + a1[(size_t)j * 4 + 1] * W1[64 + l]
            + a1[(size_t)j * 4 + 2] * W1[128 + l];
    h[(size_t)j * 64 + l] = fmaxf(v, 0.f);
}

// ---- 64-wide aggregation: wave per node, lane = feature ----
__global__ __launch_bounds__(256) void agg64_kernel(const float* __restrict__ h, const float* __restrict__ dinv,
                                                    const int* __restrict__ offs, const int* __restrict__ cnt,
                                                    const int* __restrict__ csr, float* __restrict__ a, int N) {
    int j = blockIdx.x * 4 + (threadIdx.x >> 6);
    int l = threadIdx.x & 63;
    if (j >= N) return;
    float dj = dinv[j];
    float acc = dj * h[(size_t)j * 64 + l];
    int off = offs[j], deg = cnt[j];
    int i = 0;
    for (; i + 1 < deg; i += 2) {
        int s0 = csr[off + i], s1 = csr[off + i + 1];
        float d0 = dinv[s0], d1 = dinv[s1];
        acc += d0 * h[(size_t)s0 * 64 + l];
        acc += d1 * h[(size_t)s1 * 64 + l];
    }
    if (i < deg) {
        int s0 = csr[off + i];
        acc += dinv[s0] * h[(size_t)s0 * 64 + l];
    }
    a[(size_t)j * 64 + l] = dj * acc;
}

// ---- 64x64 matmul, register-tiled: block = 128 nodes x 64 cols, thread = 8x4.
//      POOL=1: fuse mean-pool accumulation instead of storing h3. ----
template <int POOL>
__global__ __launch_bounds__(256) void mm64_kernel(const float* __restrict__ A, const float* __restrict__ W,
                                                   const float* __restrict__ bias, float* __restrict__ out,
                                                   float* __restrict__ pool, int N) {
    __shared__ float aS[64 * 132];   // k-major transposed A tile, pad 132 vs 128
    __shared__ float Ws[64 * 68];    // W tile, pad 68 vs 64
    const int t = threadIdx.x;
    const int nb = blockIdx.x * 128;

    #pragma unroll
    for (int it = 0; it < 16; ++it) {
        int flat = it * 256 + t;
        Ws[(flat >> 6) * 68 + (flat & 63)] = W[flat];
    }
    #pragma unroll
    for (int it = 0; it < 8; ++it) {
        int f4 = it * 256 + t;
        int n = f4 >> 4, kb = (f4 & 15) << 2;
        int gn = nb + n;
        float4 v = make_float4(0.f, 0.f, 0.f, 0.f);
        if (gn < N) v = *(const float4*)&A[(size_t)gn * 64 + kb];
        aS[(kb + 0) * 132 + n] = v.x;
        aS[(kb + 1) * 132 + n] = v.y;
        aS[(kb + 2) * 132 + n] = v.z;
        aS[(kb + 3) * 132 + n] = v.w;
    }
    __syncthreads();

    const int tx = t & 15, ty = t >> 4;   // cols 4*tx..+3, nodes 8*ty..+7
    float4 acc[8];
    #pragma unroll
    for (int i = 0; i < 8; ++i) acc[i] = make_float4(0.f, 0.f, 0.f, 0.f);

    #pragma unroll 4
    for (int k = 0; k < 64; ++k) {
        float4 w4 = *(const float4*)&Ws[k * 68 + (tx << 2)];
        float4 a0 = *(const float4*)&aS[k * 132 + (ty << 3)];
        float4 a1 = *(const float4*)&aS[k * 132 + (ty << 3) + 4];
        float av0 = a0.x, av1 = a0.y, av2 = a0.z, av3 = a0.w;
        float av4 = a1.x, av5 = a1.y, av6 = a1.z, av7 = a1.w;
        acc[0].x += av0 * w4.x; acc[0].y += av0 * w4.y; acc[0].z += av0 * w4.z; acc[0].w += av0 * w4.w;
        acc[1].x += av1 * w4.x; acc[1].y += av1 * w4.y; acc[1].z += av1 * w4.z; acc[1].w += av1 * w4.w;
        acc[2].x += av2 * w4.x; acc[2].y += av2 * w4.y; acc[2].z += av2 * w4.z; acc[2].w += av2 * w4.w;
        acc[3].x += av3 * w4.x; acc[3].y += av3 * w4.y; acc[3].z += av3 * w4.z; acc[3].w += av3 * w4.w;
        acc[4].x += av4 * w4.x; acc[4].y += av4 * w4.y; acc[4].z += av4 * w4.z; acc[4].w += av4 * w4.w;
        acc[5].x += av5 * w4.x; acc[5].y += av5 * w4.y; acc[5].z += av5 * w4.z; acc[5].w += av5 * w4.w;
        acc[6].x += av6 * w4.x; acc[6].y += av6 * w4.y; acc[6].z += av6 * w4.z; acc[6].w += av6 * w4.w;
        acc[7].x += av7 * w4.x; acc[7].y += av7 * w4.y; acc[7].z += av7 * w4.z; acc[7].w += av7 * w4.w;
    }

    float4 bb = *(const float4*)&bias[tx << 2];
    if (POOL) {
        float4 ps = make_float4(0.f, 0.f, 0.f, 0.f);
        #pragma unroll
        for (int i = 0; i < 8; ++i) {
            int gn = nb + (ty << 3) + i;
            if (gn < N) {
                ps.x += fmaxf(acc[i].x + bb.x, 0.f);
                ps.y += fmaxf(acc[i].y + bb.y, 0.f);
                ps.z += fmaxf(acc[i].z + bb.z, 0.f);
                ps.w += fmaxf(acc[i].w + bb.w, 0.f);
            }
        }
        __syncthreads();                  // done reading aS; reuse as reduce scratch
        float* red = aS;
        *(float4*)&red[t * 4] = ps;
        __syncthreads();
        if (ty == 0) {                    // t == tx, 16 threads
            float4 s = make_float4(0.f, 0.f, 0.f, 0.f);
            for (int i = 0; i < 16; ++i) {
                float4 q = *(const float4*)&red[(i * 16 + tx) * 4];
                s.x += q.x; s.y += q.y; s.z += q.z; s.w += q.w;
            }
            atomicAdd(&pool[(tx << 2) + 0], s.x);
            atomicAdd(&pool[(tx << 2) + 1], s.y);
            atomicAdd(&pool[(tx << 2) + 2], s.z);
            atomicAdd(&pool[(tx << 2) + 3], s.w);
        }
    } else {
        #pragma unroll
        for (int i = 0; i < 8; ++i) {
            int gn = nb + (ty << 3) + i;
            if (gn < N) {
                float4 r;
                r.x = fmaxf(acc[i].x + bb.x, 0.f);
                r.y = fmaxf(acc[i].y + bb.y, 0.f);
                r.z = fmaxf(acc[i].z + bb.z, 0.f);
                r.w = fmaxf(acc[i].w + bb.w, 0.f);
                *(float4*)&out[(size_t)gn * 64 + (tx << 2)] = r;
            }
        }
    }
}

__global__ __launch_bounds__(64) void final_kernel(const float* __restrict__ pool, const float* __restrict__ Wfc,
                                                   const float* __restrict__ bfc, float* __restrict__ out, int N) {
    int t = threadIdx.x;
    if (t < 24) {
        float inv = 1.0f / (float)N;
        float s = bfc[t];
        for (int c = 0; c < 64; ++c) s += pool[c] * inv * Wfc[c * 24 + t];
        out[t] = tanhf(s);
    }
}

extern "C" void kernel_launch(void* const* d_in, const int* in_sizes, int n_in,
                              void* d_out, int out_size, void* d_ws, size_t ws_size,
                              hipStream_t stream) {
    const float* x   = (const float*)d_in[0];
    const int*   ei  = (const int*)d_in[1];     // (2,E): row0 = src, row1 = dst
    // d_in[2] = batch (all zeros) -- unused
    const float* W1  = (const float*)d_in[3];
    const float* b1  = (const float*)d_in[4];
    const float* W2  = (const float*)d_in[5];
    const float* b2  = (const float*)d_in[6];
    const float* W3  = (const float*)d_in[7];
    const float* b3  = (const float*)d_in[8];
    const float* Wfc = (const float*)d_in[9];
    const float* bfc = (const float*)d_in[10];
    float* out = (float*)d_out;

    const int N = in_sizes[2];          // batch length = num nodes
    const int E = in_sizes[1] / 2;

    // workspace carve-up (ws re-poisoned 0xAA each call -> memset what needs zeros)
    size_t off = 0;
    auto take = [&](size_t bytes) -> char* {
        char* p = (char*)d_ws + off;
        off = ALIGN256(off + bytes);
        return p;
    };
    int*   cnt   = (int*)  take((size_t)N * 4);
    float* dinv  = (float*)take((size_t)N * 4);
    int*   offs  = (int*)  take((size_t)N * 4);
    int*   cur   = (int*)  take((size_t)N * 4);
    int*   bsum  = (int*)  take(512 * 4);
    int*   bbase = (int*)  take(512 * 4);
    float* pool  = (float*)take(64 * 4);
    int*   csr   = (int*)  take((size_t)E * 4);
    float* hbuf  = (float*)take((size_t)N * 64 * 4);
    float* abuf  = (float*)take((size_t)N * 64 * 4);
    (void)ws_size; (void)n_in; (void)out_size;

    const int NB = (N + 1023) / 1024;   // <= 512 for N <= 512k

    hipMemsetAsync(cnt, 0, (size_t)N * 4, stream);
    hipMemsetAsync(pool, 0, 64 * 4, stream);

    deg_kernel <<<(E + 255) / 256, 256, 0, stream>>>(ei + E, cnt, E);
    dinv_kernel<<<(N + 255) / 256, 256, 0, stream>>>(cnt, dinv, N);
    scan1_kernel<<<NB, 256, 0, stream>>>(cnt, bsum, N);
    scan2_kernel<<<1, 512, 0, stream>>>(bsum, bbase, NB);
    scan3_kernel<<<NB, 256, 0, stream>>>(cnt, bbase, offs, cur, N);
    fill_kernel<<<(E + 255) / 256, 256, 0, stream>>>(ei, cur, csr, E);

    // layer 1: a1 = S@x (3-wide), h = relu(a1@W1 + b1)
    agg1_kernel<<<(N + 255) / 256, 256, 0, stream>>>(x, dinv, offs, cnt, csr, abuf, N);
    mm1_kernel <<<(N + 3) / 4, 256, 0, stream>>>(abuf, W1, b1, hbuf, N);

    // layer 2
    agg64_kernel<<<(N + 3) / 4, 256, 0, stream>>>(hbuf, dinv, offs, cnt, csr, abuf, N);
    mm64_kernel<0><<<(N + 127) / 128, 256, 0, stream>>>(abuf, W2, b2, hbuf, nullptr, N);

    // layer 3 (matmul fused with mean-pool accumulation)
    agg64_kernel<<<(N + 3) / 4, 256, 0, stream>>>(hbuf, dinv, offs, cnt, csr, abuf, N);
    mm64_kernel<1><<<(N + 127) / 128, 256, 0, stream>>>(abuf, W3, b3, nullptr, pool, N);

    final_kernel<<<1, 64, 0, stream>>>(pool, Wfc, bfc, out, N);
}